// Round 1
// baseline (2142.010 us; speedup 1.0000x reference)
//
#include <hip/hip_runtime.h>
#include <hip/hip_bf16.h>
#include <math.h>

#define D_MODEL 1024
#define D_INNER 2048
#define DT_RANK 64
#define D_STATE 16
#define D_CONV  4
#define BATCH   2
#define SEQLEN  1024
#define NTOK    (BATCH * SEQLEN)     // 2048 rows
#define XDBL_W  (DT_RANK + 2 * D_STATE)  // 96

// ---------------- Generic fp32 GEMM: C[M,N] = A[M,K] * B[N,K]^T ----------------
// act: 0 = none, 1 = softplus(v + bias[n])
#define BM 64
#define BN 64
#define BK 16
#define TM 4
#define TN 4

__global__ __launch_bounds__(256) void gemm_nt(
    const float* __restrict__ A, int lda,
    const float* __restrict__ B, int ldb,
    float* __restrict__ C, int ldc,
    int M, int N, int K,
    const float* __restrict__ bias, int act)
{
    __shared__ float As[BM][BK + 1];
    __shared__ float Bs[BN][BK + 1];

    const int tid = threadIdx.x;            // 0..255
    const int tx = tid & 15;                // 0..15
    const int ty = tid >> 4;                // 0..15
    const int bm = blockIdx.x * BM;
    const int bn = blockIdx.y * BN;

    float c[TM][TN] = {};

    const int lcol = tid & 15;              // k within tile
    const int lrow = tid >> 4;              // row base

    for (int k0 = 0; k0 < K; k0 += BK) {
        #pragma unroll
        for (int r = 0; r < 4; ++r) {
            int row = lrow + r * 16;
            int gk = k0 + lcol;
            int gm = bm + row;
            int gn = bn + row;
            As[row][lcol] = (gm < M && gk < K) ? A[(size_t)gm * lda + gk] : 0.f;
            Bs[row][lcol] = (gn < N && gk < K) ? B[(size_t)gn * ldb + gk] : 0.f;
        }
        __syncthreads();

        #pragma unroll
        for (int kk = 0; kk < BK; ++kk) {
            float a[TM], b[TN];
            #pragma unroll
            for (int i = 0; i < TM; ++i) a[i] = As[ty * TM + i][kk];
            #pragma unroll
            for (int j = 0; j < TN; ++j) b[j] = Bs[tx * TN + j][kk];
            #pragma unroll
            for (int i = 0; i < TM; ++i)
                #pragma unroll
                for (int j = 0; j < TN; ++j)
                    c[i][j] = fmaf(a[i], b[j], c[i][j]);
        }
        __syncthreads();
    }

    #pragma unroll
    for (int i = 0; i < TM; ++i) {
        int gm = bm + ty * TM + i;
        if (gm >= M) continue;
        #pragma unroll
        for (int j = 0; j < TN; ++j) {
            int gn = bn + tx * TN + j;
            if (gn >= N) continue;
            float v = c[i][j];
            if (act == 1) {
                v += bias[gn];
                v = (v > 20.f) ? v : log1pf(expf(v));   // softplus
            }
            C[(size_t)gm * ldc + gn] = v;
        }
    }
}

// ---------------- Depthwise causal conv (K=4) + SiLU ----------------
// xand: (NTOK, 2*D_INNER); xi part = cols [0, D_INNER)
// xi_out: (NTOK, D_INNER)
__global__ __launch_bounds__(256) void conv_silu_kernel(
    const float* __restrict__ xand,
    const float* __restrict__ cw,   // (D_INNER, 1, 4)
    const float* __restrict__ cb,   // (D_INNER,)
    float* __restrict__ xi_out)
{
    int gid = blockIdx.x * 256 + threadIdx.x;
    if (gid >= NTOK * D_INNER) return;
    int d = gid & (D_INNER - 1);
    int row = gid >> 11;            // D_INNER = 2048 = 2^11
    int l = row & (SEQLEN - 1);

    float acc = cb[d];
    #pragma unroll
    for (int k = 0; k < D_CONV; ++k) {
        int ls = l + k - (D_CONV - 1);
        if (ls >= 0) {
            acc = fmaf(cw[d * D_CONV + k],
                       xand[(size_t)(row + k - (D_CONV - 1)) * (2 * D_INNER) + d],
                       acc);
        }
    }
    // silu
    float s = acc / (1.f + expf(-acc));
    xi_out[gid] = s;
}

// ---------------- Selective scan ----------------
// one thread per (b, d); h[16] in registers; sequential over l
__global__ __launch_bounds__(256) void scan_kernel(
    const float* __restrict__ delta,   // (NTOK, D_INNER)
    const float* __restrict__ xi,      // (NTOK, D_INNER)  == u
    const float* __restrict__ xdbl,    // (NTOK, 96): [0..64) dt, [64..80) B, [80..96) C
    const float* __restrict__ A_log,   // (D_INNER, 16)
    const float* __restrict__ Dp,      // (D_INNER,)
    float* __restrict__ y)             // (NTOK, D_INNER)
{
    int t = blockIdx.x * 256 + threadIdx.x;   // 0 .. B*D_INNER-1
    if (t >= BATCH * D_INNER) return;
    int d = t & (D_INNER - 1);
    int b = t >> 11;

    float Arow[D_STATE];
    #pragma unroll
    for (int n = 0; n < D_STATE; ++n) Arow[n] = -expf(A_log[d * D_STATE + n]);
    float Dv = Dp[d];

    float h[D_STATE] = {};

    for (int l = 0; l < SEQLEN; ++l) {
        size_t row = (size_t)b * SEQLEN + l;
        float dl = delta[row * D_INNER + d];
        float u  = xi[row * D_INNER + d];
        float du = dl * u;
        const float* bc = xdbl + row * XDBL_W;
        float acc = 0.f;
        #pragma unroll
        for (int n = 0; n < D_STATE; ++n) {
            float dA = expf(dl * Arow[n]);
            h[n] = fmaf(dA, h[n], du * bc[DT_RANK + n]);
            acc = fmaf(h[n], bc[DT_RANK + D_STATE + n], acc);
        }
        y[row * D_INNER + d] = fmaf(u, Dv, acc);
    }
}

// ---------------- Gate: gated = y * silu(res) ----------------
__global__ __launch_bounds__(256) void gate_kernel(
    const float* __restrict__ ys,
    const float* __restrict__ xand,    // res = cols [D_INNER, 2*D_INNER)
    float* __restrict__ gated)
{
    int gid = blockIdx.x * 256 + threadIdx.x;
    if (gid >= NTOK * D_INNER) return;
    int d = gid & (D_INNER - 1);
    int row = gid >> 11;
    float r = xand[(size_t)row * (2 * D_INNER) + D_INNER + d];
    float s = r / (1.f + expf(-r));
    gated[gid] = ys[gid] * s;
}

extern "C" void kernel_launch(void* const* d_in, const int* in_sizes, int n_in,
                              void* d_out, int out_size, void* d_ws, size_t ws_size,
                              hipStream_t stream) {
    const float* x          = (const float*)d_in[0];
    const float* in_proj_w  = (const float*)d_in[1];
    const float* conv_w     = (const float*)d_in[2];
    const float* conv_b     = (const float*)d_in[3];
    const float* x_proj_w   = (const float*)d_in[4];
    const float* dt_proj_w  = (const float*)d_in[5];
    const float* dt_proj_b  = (const float*)d_in[6];
    const float* A_log      = (const float*)d_in[7];
    const float* Dp         = (const float*)d_in[8];
    const float* out_proj_w = (const float*)d_in[9];
    float* out = (float*)d_out;

    // workspace layout (floats)
    float* ws = (float*)d_ws;
    size_t off = 0;
    float* xand  = ws + off; off += (size_t)NTOK * 2 * D_INNER;   // 8.39M
    float* xi    = ws + off; off += (size_t)NTOK * D_INNER;       // 4.19M
    float* xdbl  = ws + off; off += (size_t)NTOK * XDBL_W;        // 0.20M
    float* delta = ws + off; off += (size_t)NTOK * D_INNER;       // 4.19M
    float* yscan = ws + off; off += (size_t)NTOK * D_INNER;       // 4.19M
    float* gated = delta;   // delta dead after scan; reuse

    dim3 blk(256);

    // 1) in_proj: xand(2048, 4096) = x(2048,1024) @ in_proj_w(4096,1024)^T
    {
        dim3 grid(NTOK / BM, (2 * D_INNER) / BN);
        gemm_nt<<<grid, blk, 0, stream>>>(x, D_MODEL, in_proj_w, D_MODEL,
                                          xand, 2 * D_INNER,
                                          NTOK, 2 * D_INNER, D_MODEL, nullptr, 0);
    }

    // 2) conv + silu -> xi
    {
        int total = NTOK * D_INNER;
        conv_silu_kernel<<<dim3((total + 255) / 256), blk, 0, stream>>>(xand, conv_w, conv_b, xi);
    }

    // 3) x_proj: xdbl(2048, 96) = xi(2048,2048) @ x_proj_w(96,2048)^T
    {
        dim3 grid(NTOK / BM, (XDBL_W + BN - 1) / BN);
        gemm_nt<<<grid, blk, 0, stream>>>(xi, D_INNER, x_proj_w, D_INNER,
                                          xdbl, XDBL_W,
                                          NTOK, XDBL_W, D_INNER, nullptr, 0);
    }

    // 4) dt_proj + bias + softplus: delta(2048, 2048) = softplus(xdbl[:, :64] @ dt_proj_w(2048,64)^T + b)
    {
        dim3 grid(NTOK / BM, D_INNER / BN);
        gemm_nt<<<grid, blk, 0, stream>>>(xdbl, XDBL_W, dt_proj_w, DT_RANK,
                                          delta, D_INNER,
                                          NTOK, D_INNER, DT_RANK, dt_proj_b, 1);
    }

    // 5) selective scan -> yscan
    {
        int total = BATCH * D_INNER;   // 4096
        scan_kernel<<<dim3(total / 256), blk, 0, stream>>>(delta, xi, xdbl, A_log, Dp, yscan);
    }

    // 6) gate -> gated (reuses delta buffer)
    {
        int total = NTOK * D_INNER;
        gate_kernel<<<dim3((total + 255) / 256), blk, 0, stream>>>(yscan, xand, gated);
    }

    // 7) out_proj: out(2048, 1024) = gated(2048,2048) @ out_proj_w(1024,2048)^T
    {
        dim3 grid(NTOK / BM, D_MODEL / BN);
        gemm_nt<<<grid, blk, 0, stream>>>(gated, D_INNER, out_proj_w, D_INNER,
                                          out, D_MODEL,
                                          NTOK, D_MODEL, D_INNER, nullptr, 0);
    }
}

// Round 2
// 919.727 us; speedup vs baseline: 2.3290x; 2.3290x over previous
//
#include <hip/hip_runtime.h>
#include <hip/hip_bf16.h>
#include <math.h>

#define D_MODEL 1024
#define D_INNER 2048
#define DT_RANK 64
#define D_STATE 16
#define D_CONV  4
#define BATCH   2
#define SEQLEN  1024
#define NTOK    (BATCH * SEQLEN)         // 2048 rows
#define XDBL_W  (DT_RANK + 2 * D_STATE)  // 96
#define NC      8                        // scan chunks per sequence
#define CT      (SEQLEN / NC)            // 128 timesteps per chunk

// ---------------- Small fp32 GEMM (for x_proj, N=96): C[M,N] = A[M,K]*B[N,K]^T ----------------
#define BM 64
#define BN 64
#define BK 16
#define TM 4
#define TN 4

__global__ __launch_bounds__(256) void gemm_nt(
    const float* __restrict__ A, int lda,
    const float* __restrict__ B, int ldb,
    float* __restrict__ C, int ldc,
    int M, int N, int K)
{
    __shared__ float As[BM][BK + 1];
    __shared__ float Bs[BN][BK + 1];

    const int tid = threadIdx.x;
    const int tx = tid & 15;
    const int ty = tid >> 4;
    const int bm = blockIdx.x * BM;
    const int bn = blockIdx.y * BN;

    float c[TM][TN] = {};
    const int lcol = tid & 15;
    const int lrow = tid >> 4;

    for (int k0 = 0; k0 < K; k0 += BK) {
        #pragma unroll
        for (int r = 0; r < 4; ++r) {
            int row = lrow + r * 16;
            int gk = k0 + lcol;
            int gm = bm + row;
            int gn = bn + row;
            As[row][lcol] = (gm < M && gk < K) ? A[(size_t)gm * lda + gk] : 0.f;
            Bs[row][lcol] = (gn < N && gk < K) ? B[(size_t)gn * ldb + gk] : 0.f;
        }
        __syncthreads();
        #pragma unroll
        for (int kk = 0; kk < BK; ++kk) {
            float a[TM], b[TN];
            #pragma unroll
            for (int i = 0; i < TM; ++i) a[i] = As[ty * TM + i][kk];
            #pragma unroll
            for (int j = 0; j < TN; ++j) b[j] = Bs[tx * TN + j][kk];
            #pragma unroll
            for (int i = 0; i < TM; ++i)
                #pragma unroll
                for (int j = 0; j < TN; ++j)
                    c[i][j] = fmaf(a[i], b[j], c[i][j]);
        }
        __syncthreads();
    }

    #pragma unroll
    for (int i = 0; i < TM; ++i) {
        int gm = bm + ty * TM + i;
        if (gm >= M) continue;
        #pragma unroll
        for (int j = 0; j < TN; ++j) {
            int gn = bn + tx * TN + j;
            if (gn >= N) continue;
            C[(size_t)gm * ldc + gn] = c[i][j];
        }
    }
}

// ---------------- Big fp32 GEMM (128x128x16, 8x8/thread) ----------------
// Requires M%128==0, N%128==0, K%16==0. act: 0=none, 1=softplus(v+bias[n])
#define GBM 128
#define GBN 128
#define GBK 16
#define GPAD 4   // row length 132 floats: write conflicts 2-way (free), 16B aligned

__global__ __launch_bounds__(256) void gemm_nt_big(
    const float* __restrict__ A, int lda,
    const float* __restrict__ B, int ldb,
    float* __restrict__ C, int ldc,
    int K,
    const float* __restrict__ bias, int act)
{
    __shared__ float As[GBK][GBM + GPAD];
    __shared__ float Bs[GBK][GBN + GPAD];

    const int tid = threadIdx.x;
    const int tx = tid & 15;      // N subtile
    const int ty = tid >> 4;      // M subtile
    const int bm = blockIdx.x * GBM;
    const int bn = blockIdx.y * GBN;

    const int lcol = tid & 15;    // k within tile
    const int lrow = tid >> 4;    // 0..15

    float c[8][8] = {};

    for (int k0 = 0; k0 < K; k0 += GBK) {
        #pragma unroll
        for (int r = 0; r < 8; ++r) {
            As[lcol][lrow + r * 16] = A[(size_t)(bm + lrow + r * 16) * lda + k0 + lcol];
            Bs[lcol][lrow + r * 16] = B[(size_t)(bn + lrow + r * 16) * ldb + k0 + lcol];
        }
        __syncthreads();

        #pragma unroll
        for (int kk = 0; kk < GBK; ++kk) {
            float4 a0 = *(const float4*)&As[kk][ty * 8];
            float4 a1 = *(const float4*)&As[kk][ty * 8 + 4];
            float4 b0 = *(const float4*)&Bs[kk][tx * 8];
            float4 b1 = *(const float4*)&Bs[kk][tx * 8 + 4];
            float av[8] = {a0.x, a0.y, a0.z, a0.w, a1.x, a1.y, a1.z, a1.w};
            float bv[8] = {b0.x, b0.y, b0.z, b0.w, b1.x, b1.y, b1.z, b1.w};
            #pragma unroll
            for (int i = 0; i < 8; ++i)
                #pragma unroll
                for (int j = 0; j < 8; ++j)
                    c[i][j] = fmaf(av[i], bv[j], c[i][j]);
        }
        __syncthreads();
    }

    #pragma unroll
    for (int i = 0; i < 8; ++i) {
        int gm = bm + ty * 8 + i;
        #pragma unroll
        for (int j = 0; j < 8; ++j) {
            int gn = bn + tx * 8 + j;
            float v = c[i][j];
            if (act == 1) {
                v += bias[gn];
                v = (v > 20.f) ? v : log1pf(expf(v));
            }
            C[(size_t)gm * ldc + gn] = v;
        }
    }
}

// ---------------- Depthwise causal conv (K=4) + SiLU ----------------
__global__ __launch_bounds__(256) void conv_silu_kernel(
    const float* __restrict__ xand,
    const float* __restrict__ cw,
    const float* __restrict__ cb,
    float* __restrict__ xi_out)
{
    int gid = blockIdx.x * 256 + threadIdx.x;
    if (gid >= NTOK * D_INNER) return;
    int d = gid & (D_INNER - 1);
    int row = gid >> 11;
    int l = row & (SEQLEN - 1);

    float acc = cb[d];
    #pragma unroll
    for (int k = 0; k < D_CONV; ++k) {
        int ls = l + k - (D_CONV - 1);
        if (ls >= 0) {
            acc = fmaf(cw[d * D_CONV + k],
                       xand[(size_t)(row + k - (D_CONV - 1)) * (2 * D_INNER) + d],
                       acc);
        }
    }
    float s = acc / (1.f + expf(-acc));
    xi_out[gid] = s;
}

// ---------------- Chunked selective scan ----------------
// thread g: n = g&15, d = (g>>4)&2047, c = (g>>15)&(NC-1), b = g>>18
// phase1: per-chunk h_end (from h=0) and P = prod(dA) over the chunk
__global__ __launch_bounds__(256) void scan_phase1(
    const float* __restrict__ delta,
    const float* __restrict__ xi,
    const float* __restrict__ xdbl,
    const float* __restrict__ A_log,
    float* __restrict__ hend,
    float* __restrict__ Pprod)
{
    int g = blockIdx.x * 256 + threadIdx.x;
    int n = g & 15;
    int d = (g >> 4) & (D_INNER - 1);
    int c = (g >> 15) & (NC - 1);
    int b = g >> 18;

    float Aval = -expf(A_log[d * D_STATE + n]);
    float h = 0.f, P = 1.f;
    size_t rowbase = (size_t)b * SEQLEN + c * CT;

    for (int t = 0; t < CT; ++t) {
        size_t row = rowbase + t;
        float dl = delta[row * D_INNER + d];
        float u  = xi[row * D_INNER + d];
        float Bv = xdbl[row * XDBL_W + DT_RANK + n];
        float dA = expf(dl * Aval);
        h = fmaf(dA, h, dl * u * Bv);
        P *= dA;
    }
    size_t idx = (((size_t)b * NC + c) * D_INNER + d) * D_STATE + n;
    hend[idx] = h;
    Pprod[idx] = P;
}

// phase2: prefix across chunks; rewrites hend in-place to become Hin (incoming state)
__global__ __launch_bounds__(256) void scan_phase2(
    float* __restrict__ hend, const float* __restrict__ Pprod)
{
    int g = blockIdx.x * 256 + threadIdx.x;   // B*D_INNER*16 = 65536
    int n = g & 15;
    int d = (g >> 4) & (D_INNER - 1);
    int b = g >> 15;

    float Hc = 0.f;
    for (int c = 0; c < NC; ++c) {
        size_t idx = (((size_t)b * NC + c) * D_INNER + d) * D_STATE + n;
        float he = hend[idx];
        float Pc = Pprod[idx];
        hend[idx] = Hc;            // incoming state for chunk c
        Hc = fmaf(Pc, Hc, he);
    }
}

// phase3: recompute within chunk from Hin, reduce over states, write y
__global__ __launch_bounds__(256) void scan_phase3(
    const float* __restrict__ delta,
    const float* __restrict__ xi,
    const float* __restrict__ xdbl,
    const float* __restrict__ A_log,
    const float* __restrict__ Dp,
    const float* __restrict__ Hin,
    float* __restrict__ y)
{
    int g = blockIdx.x * 256 + threadIdx.x;
    int n = g & 15;
    int d = (g >> 4) & (D_INNER - 1);
    int c = (g >> 15) & (NC - 1);
    int b = g >> 18;

    float Aval = -expf(A_log[d * D_STATE + n]);
    float Dv = Dp[d];
    size_t idx = (((size_t)b * NC + c) * D_INNER + d) * D_STATE + n;
    float h = Hin[idx];
    size_t rowbase = (size_t)b * SEQLEN + c * CT;

    for (int t = 0; t < CT; ++t) {
        size_t row = rowbase + t;
        float dl = delta[row * D_INNER + d];
        float u  = xi[row * D_INNER + d];
        float Bv = xdbl[row * XDBL_W + DT_RANK + n];
        float Cv = xdbl[row * XDBL_W + DT_RANK + D_STATE + n];
        float dA = expf(dl * Aval);
        h = fmaf(dA, h, dl * u * Bv);
        float sum = h * Cv;
        sum += __shfl_xor(sum, 1);
        sum += __shfl_xor(sum, 2);
        sum += __shfl_xor(sum, 4);
        sum += __shfl_xor(sum, 8);
        if (n == 0) y[row * D_INNER + d] = fmaf(u, Dv, sum);
    }
}

// ---------------- Gate: gated = y * silu(res) ----------------
__global__ __launch_bounds__(256) void gate_kernel(
    const float* __restrict__ ys,
    const float* __restrict__ xand,
    float* __restrict__ gated)
{
    int gid = blockIdx.x * 256 + threadIdx.x;
    if (gid >= NTOK * D_INNER) return;
    int d = gid & (D_INNER - 1);
    int row = gid >> 11;
    float r = xand[(size_t)row * (2 * D_INNER) + D_INNER + d];
    float s = r / (1.f + expf(-r));
    gated[gid] = ys[gid] * s;
}

extern "C" void kernel_launch(void* const* d_in, const int* in_sizes, int n_in,
                              void* d_out, int out_size, void* d_ws, size_t ws_size,
                              hipStream_t stream) {
    const float* x          = (const float*)d_in[0];
    const float* in_proj_w  = (const float*)d_in[1];
    const float* conv_w     = (const float*)d_in[2];
    const float* conv_b     = (const float*)d_in[3];
    const float* x_proj_w   = (const float*)d_in[4];
    const float* dt_proj_w  = (const float*)d_in[5];
    const float* dt_proj_b  = (const float*)d_in[6];
    const float* A_log      = (const float*)d_in[7];
    const float* Dp         = (const float*)d_in[8];
    const float* out_proj_w = (const float*)d_in[9];
    float* out = (float*)d_out;

    float* ws = (float*)d_ws;
    size_t off = 0;
    float* xand  = ws + off; off += (size_t)NTOK * 2 * D_INNER;
    float* xi    = ws + off; off += (size_t)NTOK * D_INNER;
    float* xdbl  = ws + off; off += (size_t)NTOK * XDBL_W;
    float* delta = ws + off; off += (size_t)NTOK * D_INNER;
    float* yscan = ws + off; off += (size_t)NTOK * D_INNER;
    float* hend  = ws + off; off += (size_t)BATCH * NC * D_INNER * D_STATE;
    float* Pprod = ws + off; off += (size_t)BATCH * NC * D_INNER * D_STATE;
    float* gated = delta;   // delta dead after scan

    dim3 blk(256);

    // 1) in_proj: xand(2048,4096) = x @ in_proj_w^T
    gemm_nt_big<<<dim3(NTOK / GBM, (2 * D_INNER) / GBN), blk, 0, stream>>>(
        x, D_MODEL, in_proj_w, D_MODEL, xand, 2 * D_INNER, D_MODEL, nullptr, 0);

    // 2) conv + silu -> xi
    conv_silu_kernel<<<dim3((NTOK * D_INNER + 255) / 256), blk, 0, stream>>>(
        xand, conv_w, conv_b, xi);

    // 3) x_proj: xdbl(2048,96) = xi @ x_proj_w^T
    gemm_nt<<<dim3(NTOK / BM, (XDBL_W + BN - 1) / BN), blk, 0, stream>>>(
        xi, D_INNER, x_proj_w, D_INNER, xdbl, XDBL_W, NTOK, XDBL_W, D_INNER);

    // 4) dt_proj + softplus: delta = softplus(xdbl[:,:64] @ dt_proj_w^T + b)
    gemm_nt_big<<<dim3(NTOK / GBM, D_INNER / GBN), blk, 0, stream>>>(
        xdbl, XDBL_W, dt_proj_w, DT_RANK, delta, D_INNER, DT_RANK, dt_proj_b, 1);

    // 5) chunked scan
    {
        int total1 = BATCH * NC * D_INNER * D_STATE;      // 524288
        scan_phase1<<<dim3(total1 / 256), blk, 0, stream>>>(
            delta, xi, xdbl, A_log, hend, Pprod);
        int total2 = BATCH * D_INNER * D_STATE;           // 65536
        scan_phase2<<<dim3(total2 / 256), blk, 0, stream>>>(hend, Pprod);
        scan_phase3<<<dim3(total1 / 256), blk, 0, stream>>>(
            delta, xi, xdbl, A_log, Dp, hend, yscan);
    }

    // 6) gate
    gate_kernel<<<dim3((NTOK * D_INNER + 255) / 256), blk, 0, stream>>>(
        yscan, xand, gated);

    // 7) out_proj: out(2048,1024) = gated @ out_proj_w^T
    gemm_nt_big<<<dim3(NTOK / GBM, D_MODEL / GBN), blk, 0, stream>>>(
        gated, D_INNER, out_proj_w, D_INNER, out, D_MODEL, D_INNER, nullptr, 0);
}

// Round 3
// 410.668 us; speedup vs baseline: 5.2159x; 2.2396x over previous
//
#include <hip/hip_runtime.h>
#include <hip/hip_bf16.h>
#include <math.h>

#define D_MODEL 1024
#define D_INNER 2048
#define DT_RANK 64
#define D_STATE 16
#define D_CONV  4
#define BATCH   2
#define SEQLEN  1024
#define NTOK    (BATCH * SEQLEN)         // 2048 rows
#define XDBL_W  (DT_RANK + 2 * D_STATE)  // 96
#define NC      8                        // scan chunks per sequence
#define CT      (SEQLEN / NC)            // 128 timesteps per chunk

typedef __attribute__((ext_vector_type(8))) short bf16x8;
typedef __attribute__((ext_vector_type(4))) float f32x4;

// ---- bf16 helpers (manual RNE, no header dependency) ----
__device__ __forceinline__ short f2bf(float v) {
    unsigned int u = __builtin_bit_cast(unsigned int, v);
    unsigned int r = (u + 0x7FFFu + ((u >> 16) & 1u)) >> 16;
    return (short)r;
}
__device__ __forceinline__ float bf2f(short s) {
    return __builtin_bit_cast(float, ((unsigned int)(unsigned short)s) << 16);
}

__device__ __forceinline__ void async16(const void* g, void* l) {
    __builtin_amdgcn_global_load_lds(
        (const __attribute__((address_space(1))) unsigned int*)g,
        (__attribute__((address_space(3))) unsigned int*)l,
        16, 0, 0);
}

// ---------------- fp32 -> [hi | lo] bf16 planes ----------------
// out row-major (R_out, 2K): [0,K) = hi, [K,2K) = lo. Rows >= R_in are zero.
__global__ __launch_bounds__(256) void to_planes(
    const float* __restrict__ in, int ld_in, int col0,
    short* __restrict__ out, int R_in, int K)
{
    int k = blockIdx.x * 256 + threadIdx.x;
    if (k >= K) return;
    int r = blockIdx.y;
    float v = 0.f;
    if (r < R_in) v = in[(size_t)r * ld_in + col0 + k];
    short hi = f2bf(v);
    short lo = f2bf(v - bf2f(hi));
    size_t base = (size_t)r * (2 * K);
    out[base + k] = hi;
    out[base + K + k] = lo;
}

// ---------------- bf16-triple MFMA GEMM ----------------
// Logical C[M,N] = A[M,K]*B[N,K]^T in ~fp32 precision via K' = 3K:
//   segment 0: Ahi*Bhi, segment 1: Alo*Bhi, segment 2: Ahi*Blo
// A2/B2 are [hi|lo] plane matrices of width 2K (shorts).
// Tile 128x128, BK=32, 4 waves (2x2), 16x16x32 MFMA. SplitK via blockIdx.z.
// act: 0 = none, 1 = softplus(v + bias[n])
__global__ __launch_bounds__(256) void gemm_mfma(
    const short* __restrict__ A2, const short* __restrict__ B2,
    float* __restrict__ C, int ldc, int K, int tilesPerSplit,
    long long czstride, const float* __restrict__ bias, int act)
{
    __shared__ bf16x8 smem[1024];       // 16 KB: A tile [0,8K), B tile [8K,16K)
    char* sA = (char*)smem;
    char* sB = (char*)smem + 8192;

    const int tid  = threadIdx.x;
    const int lane = tid & 63;
    const int wid  = tid >> 6;
    const int wr   = wid >> 1, wc = wid & 1;
    const int bm   = blockIdx.x * 128;
    const int bn   = blockIdx.y * 128;
    const int z    = blockIdx.z;
    C += (long long)z * czstride;

    const int twoK = 2 * K;
    const int kt0 = z * tilesPerSplit, kt1 = kt0 + tilesPerSplit;

    const int srow0 = wid * 32 + (lane >> 2);   // staging row (issue j adds 16)
    const int dslot = lane & 3;
    const int m16   = lane & 15;
    const int koff  = lane >> 4;

    const f32x4 fzero = {0.f, 0.f, 0.f, 0.f};
    f32x4 acc[4][4];
    #pragma unroll
    for (int i = 0; i < 4; ++i)
        #pragma unroll
        for (int j = 0; j < 4; ++j) acc[i][j] = fzero;

    for (int t = kt0; t < kt1; ++t) {
        const int kl = t * 32;
        const int seg = (kl >= K) + (kl >= twoK);
        const int kphys = kl - seg * K;
        const int aoff = (seg == 1) ? K : 0;
        const int boff = (seg == 2) ? K : 0;

        #pragma unroll
        for (int j = 0; j < 2; ++j) {
            const int row = srow0 + j * 16;
            const int ss = dslot ^ ((row >> 1) & 3);
            const size_t ga = (size_t)(bm + row) * twoK + (aoff + kphys + ss * 8);
            const size_t gb = (size_t)(bn + row) * twoK + (boff + kphys + ss * 8);
            async16(A2 + ga, sA + (size_t)(wid * 32 + j * 16) * 64);
            async16(B2 + gb, sB + (size_t)(wid * 32 + j * 16) * 64);
        }
        __syncthreads();

        bf16x8 af[4], bfr[4];
        #pragma unroll
        for (int i = 0; i < 4; ++i) {
            const int ra = wr * 64 + i * 16 + m16;
            af[i] = *(const bf16x8*)(sA + ra * 64 + ((koff ^ ((ra >> 1) & 3)) * 16));
            const int rb = wc * 64 + i * 16 + m16;
            bfr[i] = *(const bf16x8*)(sB + rb * 64 + ((koff ^ ((rb >> 1) & 3)) * 16));
        }
        #pragma unroll
        for (int i = 0; i < 4; ++i)
            #pragma unroll
            for (int j = 0; j < 4; ++j)
                acc[i][j] = __builtin_amdgcn_mfma_f32_16x16x32_bf16(af[i], bfr[j], acc[i][j], 0, 0, 0);
        __syncthreads();
    }

    #pragma unroll
    for (int i = 0; i < 4; ++i) {
        const int gm0 = bm + wr * 64 + i * 16 + koff * 4;
        #pragma unroll
        for (int j = 0; j < 4; ++j) {
            const int gn = bn + wc * 64 + j * 16 + m16;
            float bb = (act == 1) ? bias[gn] : 0.f;
            #pragma unroll
            for (int r = 0; r < 4; ++r) {
                float v = acc[i][j][r];
                if (act == 1) {
                    v += bb;
                    v = (v > 20.f) ? v : log1pf(expf(v));
                }
                C[(size_t)(gm0 + r) * ldc + gn] = v;
            }
        }
    }
}

// ---------------- split-K reduces ----------------
__global__ __launch_bounds__(256) void reduce_xdbl(
    const float* __restrict__ parts, float* __restrict__ xdbl)
{
    int gid = blockIdx.x * 256 + threadIdx.x;     // < 2048*96
    int r = gid / XDBL_W;
    int c = gid - r * XDBL_W;
    float s = 0.f;
    #pragma unroll
    for (int zz = 0; zz < 8; ++zz)
        s += parts[(size_t)zz * (NTOK * 128) + (size_t)r * 128 + c];
    xdbl[gid] = s;
}

__global__ __launch_bounds__(256) void reduce_out(
    const float* __restrict__ parts, float* __restrict__ out)
{
    int gid = blockIdx.x * 256 + threadIdx.x;     // < 2048*1024
    out[gid] = parts[gid] + parts[(size_t)NTOK * D_MODEL + gid];
}

// ---------------- conv + silu -> xi planes ----------------
__global__ __launch_bounds__(256) void conv_silu_planes(
    const float* __restrict__ xand,
    const float* __restrict__ cw,
    const float* __restrict__ cb,
    short* __restrict__ xi3)
{
    int gid = blockIdx.x * 256 + threadIdx.x;
    if (gid >= NTOK * D_INNER) return;
    int d = gid & (D_INNER - 1);
    int row = gid >> 11;
    int l = row & (SEQLEN - 1);

    float acc = cb[d];
    #pragma unroll
    for (int k = 0; k < D_CONV; ++k) {
        int ls = l + k - (D_CONV - 1);
        if (ls >= 0) {
            acc = fmaf(cw[d * D_CONV + k],
                       xand[(size_t)(row + k - (D_CONV - 1)) * (2 * D_INNER) + d],
                       acc);
        }
    }
    float s = acc / (1.f + expf(-acc));
    short hi = f2bf(s);
    short lo = f2bf(s - bf2f(hi));
    size_t base = (size_t)row * (2 * D_INNER);
    xi3[base + d] = hi;
    xi3[base + D_INNER + d] = lo;
}

// ---------------- Chunked selective scan ----------------
__global__ __launch_bounds__(256) void scan_phase1(
    const float* __restrict__ delta,
    const short* __restrict__ xi3,
    const float* __restrict__ xdbl,
    const float* __restrict__ A_log,
    float* __restrict__ hend,
    float* __restrict__ Pprod)
{
    int g = blockIdx.x * 256 + threadIdx.x;
    int n = g & 15;
    int d = (g >> 4) & (D_INNER - 1);
    int c = (g >> 15) & (NC - 1);
    int b = g >> 18;

    float Aval = -expf(A_log[d * D_STATE + n]);
    float h = 0.f, P = 1.f;
    size_t rowbase = (size_t)b * SEQLEN + c * CT;

    for (int t = 0; t < CT; ++t) {
        size_t row = rowbase + t;
        float dl = delta[row * D_INNER + d];
        size_t ub = row * (2 * D_INNER);
        float u = bf2f(xi3[ub + d]) + bf2f(xi3[ub + D_INNER + d]);
        float Bv = xdbl[row * XDBL_W + DT_RANK + n];
        float dA = expf(dl * Aval);
        h = fmaf(dA, h, dl * u * Bv);
        P *= dA;
    }
    size_t idx = (((size_t)b * NC + c) * D_INNER + d) * D_STATE + n;
    hend[idx] = h;
    Pprod[idx] = P;
}

__global__ __launch_bounds__(256) void scan_phase2(
    float* __restrict__ hend, const float* __restrict__ Pprod)
{
    int g = blockIdx.x * 256 + threadIdx.x;   // < B*D_INNER*16
    int n = g & 15;
    int d = (g >> 4) & (D_INNER - 1);
    int b = g >> 15;

    float Hc = 0.f;
    for (int c = 0; c < NC; ++c) {
        size_t idx = (((size_t)b * NC + c) * D_INNER + d) * D_STATE + n;
        float he = hend[idx];
        float Pc = Pprod[idx];
        hend[idx] = Hc;
        Hc = fmaf(Pc, Hc, he);
    }
}

__global__ __launch_bounds__(256) void scan_phase3(
    const float* __restrict__ delta,
    const short* __restrict__ xi3,
    const float* __restrict__ xdbl,
    const float* __restrict__ A_log,
    const float* __restrict__ Dp,
    const float* __restrict__ Hin,
    float* __restrict__ y)
{
    int g = blockIdx.x * 256 + threadIdx.x;
    int n = g & 15;
    int d = (g >> 4) & (D_INNER - 1);
    int c = (g >> 15) & (NC - 1);
    int b = g >> 18;

    float Aval = -expf(A_log[d * D_STATE + n]);
    float Dv = Dp[d];
    size_t idx = (((size_t)b * NC + c) * D_INNER + d) * D_STATE + n;
    float h = Hin[idx];
    size_t rowbase = (size_t)b * SEQLEN + c * CT;

    for (int t = 0; t < CT; ++t) {
        size_t row = rowbase + t;
        float dl = delta[row * D_INNER + d];
        size_t ub = row * (2 * D_INNER);
        float u = bf2f(xi3[ub + d]) + bf2f(xi3[ub + D_INNER + d]);
        float Bv = xdbl[row * XDBL_W + DT_RANK + n];
        float Cv = xdbl[row * XDBL_W + DT_RANK + D_STATE + n];
        float dA = expf(dl * Aval);
        h = fmaf(dA, h, dl * u * Bv);
        float sum = h * Cv;
        sum += __shfl_xor(sum, 1);
        sum += __shfl_xor(sum, 2);
        sum += __shfl_xor(sum, 4);
        sum += __shfl_xor(sum, 8);
        if (n == 0) y[row * D_INNER + d] = fmaf(u, Dv, sum);
    }
}

// ---------------- gate + convert to planes ----------------
__global__ __launch_bounds__(256) void gate_to_planes(
    const float* __restrict__ ys,
    const float* __restrict__ xand,
    short* __restrict__ g3)
{
    int gid = blockIdx.x * 256 + threadIdx.x;
    if (gid >= NTOK * D_INNER) return;
    int d = gid & (D_INNER - 1);
    int row = gid >> 11;
    float r = xand[(size_t)row * (2 * D_INNER) + D_INNER + d];
    float s = r / (1.f + expf(-r));
    float v = ys[gid] * s;
    short hi = f2bf(v);
    short lo = f2bf(v - bf2f(hi));
    size_t base = (size_t)row * (2 * D_INNER);
    g3[base + d] = hi;
    g3[base + D_INNER + d] = lo;
}

extern "C" void kernel_launch(void* const* d_in, const int* in_sizes, int n_in,
                              void* d_out, int out_size, void* d_ws, size_t ws_size,
                              hipStream_t stream) {
    const float* x          = (const float*)d_in[0];
    const float* in_proj_w  = (const float*)d_in[1];
    const float* conv_w     = (const float*)d_in[2];
    const float* conv_b     = (const float*)d_in[3];
    const float* x_proj_w   = (const float*)d_in[4];
    const float* dt_proj_w  = (const float*)d_in[5];
    const float* dt_proj_b  = (const float*)d_in[6];
    const float* A_log      = (const float*)d_in[7];
    const float* Dp         = (const float*)d_in[8];
    const float* out_proj_w = (const float*)d_in[9];
    float* out = (float*)d_out;

    char* base = (char*)d_ws;
    // persistent region
    float* xand  = (float*)(base + 0);               // 33,554,432
    float* yscan = (float*)(base + 33554432);        // 16,777,216 (hosts inw3 early)
    float* xdbl  = (float*)(base + 50331648);        //    786,432
    float* delta = (float*)(base + 51118080);        // 16,777,216 (hosts x3 early; gated3 late)
    short* xi3   = (short*)(base + 67895296);        // 16,777,216 (hosts outw3 late)
    float* hend  = (float*)(base + 84672512);        //  2,097,152
    float* Pprod = (float*)(base + 86769664);        //  2,097,152
    char*  Q     = base + 88866816;                  // transient region
    // transient aliases
    short* x3    = (short*)delta;                    // (2048, 2048)  steps 1-3
    short* inw3  = (short*)yscan;                    // (4096, 2048)  steps 1-3
    short* xw3   = (short*)Q;                        // (128, 4096)   1,048,576
    float* xpart = (float*)(Q + 1048576);            // 8 x 2048 x 128  8,388,608
    short* dt3   = (short*)Q;                        // (2048, 128)     524,288
    short* dtw3  = (short*)(Q + 524288);             // (2048, 128)     524,288
    short* gated3= (short*)delta;                    // (2048, 4096)  steps 12-14
    short* outw3 = (short*)xi3;                      // (1024, 4096)  steps 13-14
    float* outpart = (float*)Q;                      // 2 x 2048 x 1024 (roomy only)

    const bool roomy = ws_size >= (size_t)106 * 1024 * 1024;
    dim3 blk(256);

    // 1) x -> planes
    to_planes<<<dim3(4, NTOK), blk, 0, stream>>>(x, D_MODEL, 0, x3, NTOK, D_MODEL);
    // 2) in_proj_w -> planes
    to_planes<<<dim3(4, 2 * D_INNER), blk, 0, stream>>>(in_proj_w, D_MODEL, 0, inw3, 2 * D_INNER, D_MODEL);
    // 3) in_proj GEMM: xand(2048,4096)
    gemm_mfma<<<dim3(NTOK / 128, (2 * D_INNER) / 128, 1), blk, 0, stream>>>(
        x3, inw3, xand, 2 * D_INNER, D_MODEL, 3 * D_MODEL / 32, 0, nullptr, 0);
    // 4) conv + silu -> xi planes
    conv_silu_planes<<<dim3(NTOK * D_INNER / 256), blk, 0, stream>>>(xand, conv_w, conv_b, xi3);
    // 5) x_proj_w -> planes (pad rows 96..127 with zeros)
    to_planes<<<dim3(8, 128), blk, 0, stream>>>(x_proj_w, D_INNER, 0, xw3, XDBL_W, D_INNER);
    // 6) x_proj GEMM split-K=8 -> xpart
    gemm_mfma<<<dim3(NTOK / 128, 1, 8), blk, 0, stream>>>(
        xi3, xw3, xpart, 128, D_INNER, (3 * D_INNER / 32) / 8, (long long)NTOK * 128, nullptr, 0);
    // 7) reduce -> xdbl (2048, 96)
    reduce_xdbl<<<dim3(NTOK * XDBL_W / 256), blk, 0, stream>>>(xpart, xdbl);
    // 8) dt cols of xdbl -> planes
    to_planes<<<dim3(1, NTOK), blk, 0, stream>>>(xdbl, XDBL_W, 0, dt3, NTOK, DT_RANK);
    // 9) dt_proj_w -> planes
    to_planes<<<dim3(1, D_INNER), blk, 0, stream>>>(dt_proj_w, DT_RANK, 0, dtw3, D_INNER, DT_RANK);
    // 10) dt_proj GEMM + bias + softplus -> delta  (NOTE: delta aliases x3, dead by now)
    gemm_mfma<<<dim3(NTOK / 128, D_INNER / 128, 1), blk, 0, stream>>>(
        dt3, dtw3, delta, D_INNER, DT_RANK, 3 * DT_RANK / 32, 0, dt_proj_b, 1);
    // 11) chunked scan
    {
        int total1 = BATCH * NC * D_INNER * D_STATE;   // 524288
        scan_phase1<<<dim3(total1 / 256), blk, 0, stream>>>(delta, xi3, xdbl, A_log, hend, Pprod);
        int total2 = BATCH * D_INNER * D_STATE;        // 65536
        scan_phase2<<<dim3(total2 / 256), blk, 0, stream>>>(hend, Pprod);
        scan_phase3<<<dim3(total1 / 256), blk, 0, stream>>>(delta, xi3, xdbl, A_log, Dp, hend, yscan);
    }
    // 12) gate -> gated3 planes (overwrites delta region; delta dead)
    gate_to_planes<<<dim3(NTOK * D_INNER / 256), blk, 0, stream>>>(yscan, xand, gated3);
    // 13) out_proj_w -> planes (overwrites xi3 region; xi3 dead)
    to_planes<<<dim3(8, D_MODEL), blk, 0, stream>>>(out_proj_w, D_INNER, 0, outw3, D_MODEL, D_INNER);
    // 14/15) out_proj GEMM
    if (roomy) {
        gemm_mfma<<<dim3(NTOK / 128, D_MODEL / 128, 2), blk, 0, stream>>>(
            gated3, outw3, outpart, D_MODEL, D_INNER, (3 * D_INNER / 32) / 2,
            (long long)NTOK * D_MODEL, nullptr, 0);
        reduce_out<<<dim3(NTOK * D_MODEL / 256), blk, 0, stream>>>(outpart, out);
    } else {
        gemm_mfma<<<dim3(NTOK / 128, D_MODEL / 128, 1), blk, 0, stream>>>(
            gated3, outw3, out, D_MODEL, D_INNER, 3 * D_INNER / 32, 0, nullptr, 0);
    }
}

// Round 4
// 326.168 us; speedup vs baseline: 6.5672x; 1.2591x over previous
//
#include <hip/hip_runtime.h>
#include <hip/hip_bf16.h>
#include <math.h>

#define D_MODEL 1024
#define D_INNER 2048
#define DT_RANK 64
#define D_STATE 16
#define D_CONV  4
#define BATCH   2
#define SEQLEN  1024
#define NTOK    (BATCH * SEQLEN)         // 2048 rows
#define XDBL_W  (DT_RANK + 2 * D_STATE)  // 96
#define NC      8                        // scan chunks per sequence
#define CT      (SEQLEN / NC)            // 128 timesteps per chunk
#define XSPLIT  16                       // x_proj split-K
#define OSPLIT  4                        // out_proj split-K

typedef __attribute__((ext_vector_type(8))) short bf16x8;
typedef __attribute__((ext_vector_type(4))) float f32x4;

// ---- bf16 helpers (manual RNE) ----
__device__ __forceinline__ short f2bf(float v) {
    unsigned int u = __builtin_bit_cast(unsigned int, v);
    unsigned int r = (u + 0x7FFFu + ((u >> 16) & 1u)) >> 16;
    return (short)r;
}
__device__ __forceinline__ float bf2f(short s) {
    return __builtin_bit_cast(float, ((unsigned int)(unsigned short)s) << 16);
}

__device__ __forceinline__ void async16(const void* g, void* l) {
    __builtin_amdgcn_global_load_lds(
        (const __attribute__((address_space(1))) unsigned int*)g,
        (__attribute__((address_space(3))) unsigned int*)l,
        16, 0, 0);
}

// ---------------- fp32 -> [hi | lo] bf16 planes ----------------
__global__ __launch_bounds__(256) void to_planes(
    const float* __restrict__ in, int ld_in,
    short* __restrict__ out, int R_in, int K)
{
    int k = blockIdx.x * 256 + threadIdx.x;
    if (k >= K) return;
    int r = blockIdx.y;
    float v = 0.f;
    if (r < R_in) v = in[(size_t)r * ld_in + k];
    short hi = f2bf(v);
    short lo = f2bf(v - bf2f(hi));
    size_t base = (size_t)r * (2 * K);
    out[base + k] = hi;
    out[base + K + k] = lo;
}

// ---------------- bf16-triple MFMA GEMM, 2-phase prefetch ----------------
// Logical C[M,N] = A[M,K]*B[N,K]^T in ~fp32 via K' = 3K (Ahi*Bhi, Alo*Bhi, Ahi*Blo).
// A2/B2 are [hi|lo] plane matrices of width 2K shorts. Requires K % 64 == 0.
// Tile 128x128, BK=64, 4 waves, 16x16x32 MFMA, double-buffered LDS (64 KB),
// XCD-chunked block swizzle, split-K via blockIdx.z.
__global__ __launch_bounds__(256) void gemm_mfma(
    const short* __restrict__ A2, const short* __restrict__ B2,
    float* __restrict__ C, int ldc, int K, int tilesPerSplit,
    long long czstride, const float* __restrict__ bias, int act)
{
    __shared__ bf16x8 smem[4096];       // 64 KB: 2 x (A 16K | B 16K)
    char* smem0 = (char*)smem;

    const int tid  = threadIdx.x;
    const int lane = tid & 63;
    const int wid  = tid >> 6;
    const int wr   = wid >> 1, wc = wid & 1;

    // bijective XCD-chunked swizzle over (x,y); all our grids have nwg % 8 == 0
    const int nbx = gridDim.x;
    const int nwg = nbx * gridDim.y;
    const int flat = blockIdx.x + nbx * blockIdx.y;
    const int cpx = nwg >> 3;
    const int swz = (flat & 7) * cpx + (flat >> 3);
    const int bm = (swz % nbx) * 128;
    const int bn = (swz / nbx) * 128;

    const int z = blockIdx.z;
    C += (long long)z * czstride;

    const int twoK = 2 * K;
    const int kt0 = z * tilesPerSplit, kt1 = kt0 + tilesPerSplit;

    const int m16 = lane & 15;
    const int koff = lane >> 4;
    const int sslot = (lane & 7) ^ (lane >> 3);   // pre-swizzled global slot
    const int sdst = wid * 1024 + lane * 16;      // LDS dest (linear)

    const f32x4 fzero = {0.f, 0.f, 0.f, 0.f};
    f32x4 acc[4][4];
    #pragma unroll
    for (int i = 0; i < 4; ++i)
        #pragma unroll
        for (int j = 0; j < 4; ++j) acc[i][j] = fzero;

    auto STAGE = [&](int buf, int t) {
        const int kl = t * 64;
        const int seg = (kl >= K) + (kl >= twoK);
        const int kphys = kl - seg * K;
        const int aoff = (seg == 1) ? K : 0;
        const int boff = (seg == 2) ? K : 0;
        char* dA = smem0 + buf * 32768;
        char* dB = dA + 16384;
        #pragma unroll
        for (int r = 0; r < 4; ++r) {
            const int row = wid * 8 + (lane >> 3) + r * 32;
            const size_t ga = (size_t)(bm + row) * twoK + (aoff + kphys + sslot * 8);
            const size_t gb = (size_t)(bn + row) * twoK + (boff + kphys + sslot * 8);
            async16(A2 + ga, dA + r * 4096 + sdst);
            async16(B2 + gb, dB + r * 4096 + sdst);
        }
    };

    STAGE(0, kt0);
    __syncthreads();

    int cur = 0;
    for (int t = kt0; t < kt1; ++t) {
        if (t + 1 < kt1) STAGE(cur ^ 1, t + 1);

        const char* rA = smem0 + cur * 32768;
        const char* rB = rA + 16384;
        #pragma unroll
        for (int kk = 0; kk < 2; ++kk) {
            bf16x8 af[4], bfr[4];
            #pragma unroll
            for (int i = 0; i < 4; ++i) {
                const int ra = wr * 64 + i * 16 + m16;
                af[i] = *(const bf16x8*)(rA + ra * 128 + (((kk * 4 + koff) ^ (ra & 7)) << 4));
            }
            #pragma unroll
            for (int j = 0; j < 4; ++j) {
                const int rb = wc * 64 + j * 16 + m16;
                bfr[j] = *(const bf16x8*)(rB + rb * 128 + (((kk * 4 + koff) ^ (rb & 7)) << 4));
            }
            #pragma unroll
            for (int i = 0; i < 4; ++i)
                #pragma unroll
                for (int j = 0; j < 4; ++j)
                    acc[i][j] = __builtin_amdgcn_mfma_f32_16x16x32_bf16(af[i], bfr[j], acc[i][j], 0, 0, 0);
        }
        __syncthreads();   // drains prefetch vmcnt + protects buffer reuse
        cur ^= 1;
    }

    #pragma unroll
    for (int i = 0; i < 4; ++i) {
        const int gm0 = bm + wr * 64 + i * 16 + koff * 4;
        #pragma unroll
        for (int j = 0; j < 4; ++j) {
            const int gn = bn + wc * 64 + j * 16 + m16;
            float bb = (act == 1) ? bias[gn] : 0.f;
            #pragma unroll
            for (int r = 0; r < 4; ++r) {
                float v = acc[i][j][r];
                if (act == 1) {
                    v += bb;
                    v = (v > 20.f) ? v : log1pf(expf(v));
                }
                C[(size_t)(gm0 + r) * ldc + gn] = v;
            }
        }
    }
}

// ---------------- split-K reduces ----------------
// x_proj reduce + fused dt-plane conversion
__global__ __launch_bounds__(256) void reduce_xdbl(
    const float* __restrict__ parts, float* __restrict__ xdbl, short* __restrict__ dt3)
{
    int gid = blockIdx.x * 256 + threadIdx.x;     // < 2048*96
    int r = gid / XDBL_W;
    int c = gid - r * XDBL_W;
    float s = 0.f;
    #pragma unroll
    for (int zz = 0; zz < XSPLIT; ++zz)
        s += parts[(size_t)zz * (NTOK * 128) + (size_t)r * 128 + c];
    xdbl[gid] = s;
    if (c < DT_RANK) {
        short hi = f2bf(s);
        short lo = f2bf(s - bf2f(hi));
        dt3[(size_t)r * 128 + c] = hi;
        dt3[(size_t)r * 128 + DT_RANK + c] = lo;
    }
}

__global__ __launch_bounds__(256) void reduce_out(
    const float* __restrict__ parts, float* __restrict__ out)
{
    int gid = blockIdx.x * 256 + threadIdx.x;     // < 2048*1024
    float s = 0.f;
    #pragma unroll
    for (int zz = 0; zz < OSPLIT; ++zz)
        s += parts[(size_t)zz * (NTOK * D_MODEL) + gid];
    out[gid] = s;
}

// ---------------- conv + silu -> xi planes ----------------
__global__ __launch_bounds__(256) void conv_silu_planes(
    const float* __restrict__ xand,
    const float* __restrict__ cw,
    const float* __restrict__ cb,
    short* __restrict__ xi3)
{
    int gid = blockIdx.x * 256 + threadIdx.x;
    if (gid >= NTOK * D_INNER) return;
    int d = gid & (D_INNER - 1);
    int row = gid >> 11;
    int l = row & (SEQLEN - 1);

    float acc = cb[d];
    #pragma unroll
    for (int k = 0; k < D_CONV; ++k) {
        int ls = l + k - (D_CONV - 1);
        if (ls >= 0) {
            acc = fmaf(cw[d * D_CONV + k],
                       xand[(size_t)(row + k - (D_CONV - 1)) * (2 * D_INNER) + d],
                       acc);
        }
    }
    float s = acc / (1.f + expf(-acc));
    short hi = f2bf(s);
    short lo = f2bf(s - bf2f(hi));
    size_t base = (size_t)row * (2 * D_INNER);
    xi3[base + d] = hi;
    xi3[base + D_INNER + d] = lo;
}

// ---------------- Chunked selective scan ----------------
__global__ __launch_bounds__(256) void scan_phase1(
    const float* __restrict__ delta,
    const short* __restrict__ xi3,
    const float* __restrict__ xdbl,
    const float* __restrict__ A_log,
    float* __restrict__ hend,
    float* __restrict__ Pprod)
{
    int g = blockIdx.x * 256 + threadIdx.x;
    int n = g & 15;
    int d = (g >> 4) & (D_INNER - 1);
    int c = (g >> 15) & (NC - 1);
    int b = g >> 18;

    float Aval = -expf(A_log[d * D_STATE + n]);
    float h = 0.f, P = 1.f;
    size_t rowbase = (size_t)b * SEQLEN + c * CT;

    for (int t = 0; t < CT; ++t) {
        size_t row = rowbase + t;
        float dl = delta[row * D_INNER + d];
        size_t ub = row * (2 * D_INNER);
        float u = bf2f(xi3[ub + d]) + bf2f(xi3[ub + D_INNER + d]);
        float Bv = xdbl[row * XDBL_W + DT_RANK + n];
        float dA = expf(dl * Aval);
        h = fmaf(dA, h, dl * u * Bv);
        P *= dA;
    }
    size_t idx = (((size_t)b * NC + c) * D_INNER + d) * D_STATE + n;
    hend[idx] = h;
    Pprod[idx] = P;
}

__global__ __launch_bounds__(256) void scan_phase2(
    float* __restrict__ hend, const float* __restrict__ Pprod)
{
    int g = blockIdx.x * 256 + threadIdx.x;   // < B*D_INNER*16
    int n = g & 15;
    int d = (g >> 4) & (D_INNER - 1);
    int b = g >> 15;

    float Hc = 0.f;
    for (int c = 0; c < NC; ++c) {
        size_t idx = (((size_t)b * NC + c) * D_INNER + d) * D_STATE + n;
        float he = hend[idx];
        float Pc = Pprod[idx];
        hend[idx] = Hc;
        Hc = fmaf(Pc, Hc, he);
    }
}

__global__ __launch_bounds__(256) void scan_phase3(
    const float* __restrict__ delta,
    const short* __restrict__ xi3,
    const float* __restrict__ xdbl,
    const float* __restrict__ A_log,
    const float* __restrict__ Dp,
    const float* __restrict__ Hin,
    float* __restrict__ y)
{
    int g = blockIdx.x * 256 + threadIdx.x;
    int n = g & 15;
    int d = (g >> 4) & (D_INNER - 1);
    int c = (g >> 15) & (NC - 1);
    int b = g >> 18;

    float Aval = -expf(A_log[d * D_STATE + n]);
    float Dv = Dp[d];
    size_t idx = (((size_t)b * NC + c) * D_INNER + d) * D_STATE + n;
    float h = Hin[idx];
    size_t rowbase = (size_t)b * SEQLEN + c * CT;

    for (int t = 0; t < CT; ++t) {
        size_t row = rowbase + t;
        float dl = delta[row * D_INNER + d];
        size_t ub = row * (2 * D_INNER);
        float u = bf2f(xi3[ub + d]) + bf2f(xi3[ub + D_INNER + d]);
        float Bv = xdbl[row * XDBL_W + DT_RANK + n];
        float Cv = xdbl[row * XDBL_W + DT_RANK + D_STATE + n];
        float dA = expf(dl * Aval);
        h = fmaf(dA, h, dl * u * Bv);
        float sum = h * Cv;
        sum += __shfl_xor(sum, 1);
        sum += __shfl_xor(sum, 2);
        sum += __shfl_xor(sum, 4);
        sum += __shfl_xor(sum, 8);
        if (n == 0) y[row * D_INNER + d] = fmaf(u, Dv, sum);
    }
}

// ---------------- gate + convert to planes ----------------
__global__ __launch_bounds__(256) void gate_to_planes(
    const float* __restrict__ ys,
    const float* __restrict__ xand,
    short* __restrict__ g3)
{
    int gid = blockIdx.x * 256 + threadIdx.x;
    if (gid >= NTOK * D_INNER) return;
    int d = gid & (D_INNER - 1);
    int row = gid >> 11;
    float r = xand[(size_t)row * (2 * D_INNER) + D_INNER + d];
    float s = r / (1.f + expf(-r));
    float v = ys[gid] * s;
    short hi = f2bf(v);
    short lo = f2bf(v - bf2f(hi));
    size_t base = (size_t)row * (2 * D_INNER);
    g3[base + d] = hi;
    g3[base + D_INNER + d] = lo;
}

extern "C" void kernel_launch(void* const* d_in, const int* in_sizes, int n_in,
                              void* d_out, int out_size, void* d_ws, size_t ws_size,
                              hipStream_t stream) {
    const float* x          = (const float*)d_in[0];
    const float* in_proj_w  = (const float*)d_in[1];
    const float* conv_w     = (const float*)d_in[2];
    const float* conv_b     = (const float*)d_in[3];
    const float* x_proj_w   = (const float*)d_in[4];
    const float* dt_proj_w  = (const float*)d_in[5];
    const float* dt_proj_b  = (const float*)d_in[6];
    const float* A_log      = (const float*)d_in[7];
    const float* Dp         = (const float*)d_in[8];
    const float* out_proj_w = (const float*)d_in[9];
    float* out = (float*)d_out;

    char* base = (char*)d_ws;
    // persistent region
    float* xand  = (float*)(base + 0);               // 33,554,432 (outpart late)
    float* yscan = (float*)(base + 33554432);        // 16,777,216 (inw3 early)
    float* xdbl  = (float*)(base + 50331648);        //    786,432
    float* delta = (float*)(base + 51118080);        // 16,777,216 (x3 early; xpart mid; gated3 late)
    short* xi3   = (short*)(base + 67895296);        // 16,777,216 (outw3 late)
    float* hend  = (float*)(base + 84672512);        //  2,097,152
    float* Pprod = (float*)(base + 86769664);        //  2,097,152
    char*  Q     = base + 88866816;                  // transient (~2 MB)
    // aliases
    short* x3     = (short*)delta;                   // (2048,2048)   steps 1-3
    short* inw3   = (short*)yscan;                   // (4096,2048)   steps 1-3
    short* xw3    = (short*)Q;                       // (128,4096)    1 MB
    short* dt3    = (short*)(Q + 1048576);           // (2048,128)    0.5 MB
    short* dtw3   = (short*)(Q + 1572864);           // (2048,128)    0.5 MB
    float* xpart  = (float*)delta;                   // 16 x 2048 x 128 f32 = 16 MB
    short* gated3 = (short*)delta;                   // (2048,4096)   steps 12-14
    short* outw3  = (short*)xi3;                     // (1024,4096)   steps 13-14
    float* outpart= (float*)xand;                    // 4 x 2048 x 1024 f32 = 32 MB

    dim3 blk(256);

    // 1) x -> planes
    to_planes<<<dim3(4, NTOK), blk, 0, stream>>>(x, D_MODEL, x3, NTOK, D_MODEL);
    // 2) in_proj_w -> planes
    to_planes<<<dim3(4, 2 * D_INNER), blk, 0, stream>>>(in_proj_w, D_MODEL, inw3, 2 * D_INNER, D_MODEL);
    // 3) in_proj GEMM: xand(2048,4096)
    gemm_mfma<<<dim3(NTOK / 128, (2 * D_INNER) / 128, 1), blk, 0, stream>>>(
        x3, inw3, xand, 2 * D_INNER, D_MODEL, 3 * D_MODEL / 64, 0, nullptr, 0);
    // 4) conv + silu -> xi planes
    conv_silu_planes<<<dim3(NTOK * D_INNER / 256), blk, 0, stream>>>(xand, conv_w, conv_b, xi3);
    // 5) x_proj_w -> planes (rows 96..127 zero)
    to_planes<<<dim3(8, 128), blk, 0, stream>>>(x_proj_w, D_INNER, xw3, XDBL_W, D_INNER);
    // 6) x_proj GEMM split-K=16 -> xpart (in dead x3/delta region)
    gemm_mfma<<<dim3(NTOK / 128, 1, XSPLIT), blk, 0, stream>>>(
        xi3, xw3, xpart, 128, D_INNER, (3 * D_INNER / 64) / XSPLIT,
        (long long)NTOK * 128, nullptr, 0);
    // 7) reduce -> xdbl + dt3 planes (fused)
    reduce_xdbl<<<dim3(NTOK * XDBL_W / 256), blk, 0, stream>>>(xpart, xdbl, dt3);
    // 8) dt_proj_w -> planes
    to_planes<<<dim3(1, D_INNER), blk, 0, stream>>>(dt_proj_w, DT_RANK, dtw3, D_INNER, DT_RANK);
    // 9) dt_proj GEMM + bias + softplus -> delta (x3/xpart dead)
    gemm_mfma<<<dim3(NTOK / 128, D_INNER / 128, 1), blk, 0, stream>>>(
        dt3, dtw3, delta, D_INNER, DT_RANK, 3 * DT_RANK / 64, 0, dt_proj_b, 1);
    // 10) chunked scan
    {
        int total1 = BATCH * NC * D_INNER * D_STATE;   // 524288
        scan_phase1<<<dim3(total1 / 256), blk, 0, stream>>>(delta, xi3, xdbl, A_log, hend, Pprod);
        int total2 = BATCH * D_INNER * D_STATE;        // 65536
        scan_phase2<<<dim3(total2 / 256), blk, 0, stream>>>(hend, Pprod);
        scan_phase3<<<dim3(total1 / 256), blk, 0, stream>>>(delta, xi3, xdbl, A_log, Dp, hend, yscan);
    }
    // 11) gate -> gated3 planes (delta dead)
    gate_to_planes<<<dim3(NTOK * D_INNER / 256), blk, 0, stream>>>(yscan, xand, gated3);
    // 12) out_proj_w -> planes (xi3 dead)
    to_planes<<<dim3(8, D_MODEL), blk, 0, stream>>>(out_proj_w, D_INNER, outw3, D_MODEL, D_INNER);
    // 13) out_proj GEMM split-K=4 -> outpart (xand dead)
    gemm_mfma<<<dim3(NTOK / 128, D_MODEL / 128, OSPLIT), blk, 0, stream>>>(
        gated3, outw3, outpart, D_MODEL, D_INNER, (3 * D_INNER / 64) / OSPLIT,
        (long long)NTOK * D_MODEL, nullptr, 0);
    // 14) reduce -> out
    reduce_out<<<dim3(NTOK * D_MODEL / 256), blk, 0, stream>>>(outpart, out);
}

// Round 5
// 247.385 us; speedup vs baseline: 8.6586x; 1.3185x over previous
//
#include <hip/hip_runtime.h>
#include <hip/hip_bf16.h>
#include <math.h>

#define D_MODEL 1024
#define D_INNER 2048
#define DT_RANK 64
#define D_STATE 16
#define D_CONV  4
#define BATCH   2
#define SEQLEN  1024
#define NTOK    (BATCH * SEQLEN)         // 2048 rows
#define XDBL_W  (DT_RANK + 2 * D_STATE)  // 96
#define NC      64                       // scan chunks per sequence
#define CT      (SEQLEN / NC)            // 16 timesteps per chunk
#define XSPLIT  16                       // x_proj split-K
#define OSPLIT  4                        // out_proj split-K

typedef __attribute__((ext_vector_type(8))) short bf16x8;
typedef __attribute__((ext_vector_type(4))) float f32x4;

// ---- bf16 helpers (manual RNE) ----
__device__ __forceinline__ short f2bf(float v) {
    unsigned int u = __builtin_bit_cast(unsigned int, v);
    unsigned int r = (u + 0x7FFFu + ((u >> 16) & 1u)) >> 16;
    return (short)r;
}
__device__ __forceinline__ float bf2f(short s) {
    return __builtin_bit_cast(float, ((unsigned int)(unsigned short)s) << 16);
}

__device__ __forceinline__ void async16(const void* g, void* l) {
    __builtin_amdgcn_global_load_lds(
        (const __attribute__((address_space(1))) unsigned int*)g,
        (__attribute__((address_space(3))) unsigned int*)l,
        16, 0, 0);
}

// ---------------- fp32 -> [hi | lo] bf16 planes ----------------
__global__ __launch_bounds__(256) void to_planes(
    const float* __restrict__ in, int ld_in,
    short* __restrict__ out, int R_in, int K)
{
    int k = blockIdx.x * 256 + threadIdx.x;
    if (k >= K) return;
    int r = blockIdx.y;
    float v = 0.f;
    if (r < R_in) v = in[(size_t)r * ld_in + k];
    short hi = f2bf(v);
    short lo = f2bf(v - bf2f(hi));
    size_t base = (size_t)r * (2 * K);
    out[base + k] = hi;
    out[base + K + k] = lo;
}

// ---------------- bf16-triple MFMA GEMM, 2-phase prefetch ----------------
__global__ __launch_bounds__(256) void gemm_mfma(
    const short* __restrict__ A2, const short* __restrict__ B2,
    float* __restrict__ C, int ldc, int K, int tilesPerSplit,
    long long czstride, const float* __restrict__ bias, int act)
{
    __shared__ bf16x8 smem[4096];       // 64 KB: 2 x (A 16K | B 16K)
    char* smem0 = (char*)smem;

    const int tid  = threadIdx.x;
    const int lane = tid & 63;
    const int wid  = tid >> 6;
    const int wr   = wid >> 1, wc = wid & 1;

    const int nbx = gridDim.x;
    const int nwg = nbx * gridDim.y;
    const int flat = blockIdx.x + nbx * blockIdx.y;
    const int cpx = nwg >> 3;
    const int swz = (flat & 7) * cpx + (flat >> 3);
    const int bm = (swz % nbx) * 128;
    const int bn = (swz / nbx) * 128;

    const int z = blockIdx.z;
    C += (long long)z * czstride;

    const int twoK = 2 * K;
    const int kt0 = z * tilesPerSplit, kt1 = kt0 + tilesPerSplit;

    const int m16 = lane & 15;
    const int koff = lane >> 4;
    const int sslot = (lane & 7) ^ (lane >> 3);
    const int sdst = wid * 1024 + lane * 16;

    const f32x4 fzero = {0.f, 0.f, 0.f, 0.f};
    f32x4 acc[4][4];
    #pragma unroll
    for (int i = 0; i < 4; ++i)
        #pragma unroll
        for (int j = 0; j < 4; ++j) acc[i][j] = fzero;

    auto STAGE = [&](int buf, int t) {
        const int kl = t * 64;
        const int seg = (kl >= K) + (kl >= twoK);
        const int kphys = kl - seg * K;
        const int aoff = (seg == 1) ? K : 0;
        const int boff = (seg == 2) ? K : 0;
        char* dA = smem0 + buf * 32768;
        char* dB = dA + 16384;
        #pragma unroll
        for (int r = 0; r < 4; ++r) {
            const int row = wid * 8 + (lane >> 3) + r * 32;
            const size_t ga = (size_t)(bm + row) * twoK + (aoff + kphys + sslot * 8);
            const size_t gb = (size_t)(bn + row) * twoK + (boff + kphys + sslot * 8);
            async16(A2 + ga, dA + r * 4096 + sdst);
            async16(B2 + gb, dB + r * 4096 + sdst);
        }
    };

    STAGE(0, kt0);
    __syncthreads();

    int cur = 0;
    for (int t = kt0; t < kt1; ++t) {
        if (t + 1 < kt1) STAGE(cur ^ 1, t + 1);

        const char* rA = smem0 + cur * 32768;
        const char* rB = rA + 16384;
        #pragma unroll
        for (int kk = 0; kk < 2; ++kk) {
            bf16x8 af[4], bfr[4];
            #pragma unroll
            for (int i = 0; i < 4; ++i) {
                const int ra = wr * 64 + i * 16 + m16;
                af[i] = *(const bf16x8*)(rA + ra * 128 + (((kk * 4 + koff) ^ (ra & 7)) << 4));
            }
            #pragma unroll
            for (int j = 0; j < 4; ++j) {
                const int rb = wc * 64 + j * 16 + m16;
                bfr[j] = *(const bf16x8*)(rB + rb * 128 + (((kk * 4 + koff) ^ (rb & 7)) << 4));
            }
            #pragma unroll
            for (int i = 0; i < 4; ++i)
                #pragma unroll
                for (int j = 0; j < 4; ++j)
                    acc[i][j] = __builtin_amdgcn_mfma_f32_16x16x32_bf16(af[i], bfr[j], acc[i][j], 0, 0, 0);
        }
        __syncthreads();
        cur ^= 1;
    }

    #pragma unroll
    for (int i = 0; i < 4; ++i) {
        const int gm0 = bm + wr * 64 + i * 16 + koff * 4;
        #pragma unroll
        for (int j = 0; j < 4; ++j) {
            const int gn = bn + wc * 64 + j * 16 + m16;
            float bb = (act == 1) ? bias[gn] : 0.f;
            #pragma unroll
            for (int r = 0; r < 4; ++r) {
                float v = acc[i][j][r];
                if (act == 1) {
                    v += bb;
                    v = (v > 20.f) ? v : log1pf(__expf(v));
                }
                C[(size_t)(gm0 + r) * ldc + gn] = v;
            }
        }
    }
}

// ---------------- split-K reduces ----------------
__global__ __launch_bounds__(256) void reduce_xdbl(
    const float* __restrict__ parts, float* __restrict__ xdbl, short* __restrict__ dt3)
{
    int gid = blockIdx.x * 256 + threadIdx.x;     // < 2048*96
    int r = gid / XDBL_W;
    int c = gid - r * XDBL_W;
    float s = 0.f;
    #pragma unroll
    for (int zz = 0; zz < XSPLIT; ++zz)
        s += parts[(size_t)zz * (NTOK * 128) + (size_t)r * 128 + c];
    xdbl[gid] = s;
    if (c < DT_RANK) {
        short hi = f2bf(s);
        short lo = f2bf(s - bf2f(hi));
        dt3[(size_t)r * 128 + c] = hi;
        dt3[(size_t)r * 128 + DT_RANK + c] = lo;
    }
}

__global__ __launch_bounds__(256) void reduce_out(
    const float* __restrict__ parts, float* __restrict__ out)
{
    int gid = blockIdx.x * 256 + threadIdx.x;     // < 2048*1024
    float s = 0.f;
    #pragma unroll
    for (int zz = 0; zz < OSPLIT; ++zz)
        s += parts[(size_t)zz * (NTOK * D_MODEL) + gid];
    out[gid] = s;
}

// ---------------- conv + silu -> xi planes ----------------
__global__ __launch_bounds__(256) void conv_silu_planes(
    const float* __restrict__ xand,
    const float* __restrict__ cw,
    const float* __restrict__ cb,
    short* __restrict__ xi3)
{
    int gid = blockIdx.x * 256 + threadIdx.x;
    if (gid >= NTOK * D_INNER) return;
    int d = gid & (D_INNER - 1);
    int row = gid >> 11;
    int l = row & (SEQLEN - 1);

    float acc = cb[d];
    #pragma unroll
    for (int k = 0; k < D_CONV; ++k) {
        int ls = l + k - (D_CONV - 1);
        if (ls >= 0) {
            acc = fmaf(cw[d * D_CONV + k],
                       xand[(size_t)(row + k - (D_CONV - 1)) * (2 * D_INNER) + d],
                       acc);
        }
    }
    float s = acc / (1.f + __expf(-acc));
    short hi = f2bf(s);
    short lo = f2bf(s - bf2f(hi));
    size_t base = (size_t)row * (2 * D_INNER);
    xi3[base + d] = hi;
    xi3[base + D_INNER + d] = lo;
}

// ---------------- Chunked selective scan (state-in-registers) ----------------
// thread g: d = g & 2047, c = (g>>11) & 63, b = g >> 17.  16 states in regs.
__global__ __launch_bounds__(256) void scan_phase1(
    const float* __restrict__ delta,
    const short* __restrict__ xi3,
    const float* __restrict__ xdbl,
    const float* __restrict__ A_log,
    float* __restrict__ hend,
    float* __restrict__ Pprod)
{
    int g = blockIdx.x * 256 + threadIdx.x;
    int d = g & (D_INNER - 1);
    int c = (g >> 11) & (NC - 1);
    int b = g >> 17;

    float Arow[D_STATE], h[D_STATE], P[D_STATE];
    #pragma unroll
    for (int q = 0; q < 4; ++q) {
        f32x4 a = *(const f32x4*)&A_log[d * D_STATE + q * 4];
        #pragma unroll
        for (int j = 0; j < 4; ++j) {
            Arow[q * 4 + j] = -__expf(a[j]);
            h[q * 4 + j] = 0.f;
            P[q * 4 + j] = 1.f;
        }
    }

    size_t rowbase = (size_t)b * SEQLEN + c * CT;
    for (int t = 0; t < CT; ++t) {
        size_t row = rowbase + t;
        float dl = delta[row * D_INNER + d];
        size_t ub = row * (2 * D_INNER);
        float u = bf2f(xi3[ub + d]) + bf2f(xi3[ub + D_INNER + d]);
        float du = dl * u;
        const float* bc = xdbl + row * XDBL_W + DT_RANK;
        #pragma unroll
        for (int q = 0; q < 4; ++q) {
            f32x4 Bv = *(const f32x4*)(bc + q * 4);
            #pragma unroll
            for (int j = 0; j < 4; ++j) {
                int n = q * 4 + j;
                float dA = __expf(dl * Arow[n]);
                h[n] = fmaf(dA, h[n], du * Bv[j]);
                P[n] *= dA;
            }
        }
    }

    size_t idx = (((size_t)b * NC + c) * D_INNER + d) * D_STATE;
    #pragma unroll
    for (int q = 0; q < 4; ++q) {
        f32x4 hv = {h[q*4], h[q*4+1], h[q*4+2], h[q*4+3]};
        f32x4 pv = {P[q*4], P[q*4+1], P[q*4+2], P[q*4+3]};
        *(f32x4*)&hend[idx + q * 4] = hv;
        *(f32x4*)&Pprod[idx + q * 4] = pv;
    }
}

// phase2: prefix across chunks per (b,d,n); depth-8 load batching
__global__ __launch_bounds__(256) void scan_phase2(
    float* __restrict__ hend, const float* __restrict__ Pprod)
{
    int g = blockIdx.x * 256 + threadIdx.x;   // < B*D_INNER*16 = 65536
    int n = g & 15;
    int d = (g >> 4) & (D_INNER - 1);
    int b = g >> 15;

    const size_t cs = (size_t)D_INNER * D_STATE;
    size_t base = ((size_t)b * NC) * cs + (size_t)d * D_STATE + n;

    float Hc = 0.f;
    for (int c0 = 0; c0 < NC; c0 += 8) {
        float he[8], Pc[8];
        #pragma unroll
        for (int j = 0; j < 8; ++j) {
            he[j] = hend[base + (size_t)(c0 + j) * cs];
            Pc[j] = Pprod[base + (size_t)(c0 + j) * cs];
        }
        #pragma unroll
        for (int j = 0; j < 8; ++j) {
            hend[base + (size_t)(c0 + j) * cs] = Hc;
            Hc = fmaf(Pc[j], Hc, he[j]);
        }
    }
}

// phase3: recompute within chunk from Hin, reduce states in-register,
// fused gate: writes gated bf16 planes directly.
__global__ __launch_bounds__(256) void scan_phase3(
    const float* __restrict__ delta,
    const short* __restrict__ xi3,
    const float* __restrict__ xdbl,
    const float* __restrict__ A_log,
    const float* __restrict__ Dp,
    const float* __restrict__ Hin,
    const float* __restrict__ xand,
    short* __restrict__ g3)
{
    int g = blockIdx.x * 256 + threadIdx.x;
    int d = g & (D_INNER - 1);
    int c = (g >> 11) & (NC - 1);
    int b = g >> 17;

    float Arow[D_STATE], h[D_STATE];
    size_t idx = (((size_t)b * NC + c) * D_INNER + d) * D_STATE;
    #pragma unroll
    for (int q = 0; q < 4; ++q) {
        f32x4 a = *(const f32x4*)&A_log[d * D_STATE + q * 4];
        f32x4 hv = *(const f32x4*)&Hin[idx + q * 4];
        #pragma unroll
        for (int j = 0; j < 4; ++j) {
            Arow[q * 4 + j] = -__expf(a[j]);
            h[q * 4 + j] = hv[j];
        }
    }
    float Dv = Dp[d];

    size_t rowbase = (size_t)b * SEQLEN + c * CT;
    for (int t = 0; t < CT; ++t) {
        size_t row = rowbase + t;
        float dl = delta[row * D_INNER + d];
        size_t ub = row * (2 * D_INNER);
        float u = bf2f(xi3[ub + d]) + bf2f(xi3[ub + D_INNER + d]);
        float du = dl * u;
        const float* bc = xdbl + row * XDBL_W + DT_RANK;
        float s0 = 0.f, s1 = 0.f, s2 = 0.f, s3 = 0.f;
        #pragma unroll
        for (int q = 0; q < 4; ++q) {
            f32x4 Bv = *(const f32x4*)(bc + q * 4);
            f32x4 Cv = *(const f32x4*)(bc + D_STATE + q * 4);
            #pragma unroll
            for (int j = 0; j < 4; ++j) {
                int n = q * 4 + j;
                float dA = __expf(dl * Arow[n]);
                h[n] = fmaf(dA, h[n], du * Bv[j]);
            }
            s0 = fmaf(h[q*4],   Cv[0], s0);
            s1 = fmaf(h[q*4+1], Cv[1], s1);
            s2 = fmaf(h[q*4+2], Cv[2], s2);
            s3 = fmaf(h[q*4+3], Cv[3], s3);
        }
        float y = fmaf(u, Dv, (s0 + s1) + (s2 + s3));
        // fused gate: v = y * silu(res)
        float r = xand[row * (2 * D_INNER) + D_INNER + d];
        float sg = r / (1.f + __expf(-r));
        float v = y * sg;
        short hi = f2bf(v);
        short lo = f2bf(v - bf2f(hi));
        size_t gbase = row * (2 * D_INNER);
        g3[gbase + d] = hi;
        g3[gbase + D_INNER + d] = lo;
    }
}

extern "C" void kernel_launch(void* const* d_in, const int* in_sizes, int n_in,
                              void* d_out, int out_size, void* d_ws, size_t ws_size,
                              hipStream_t stream) {
    const float* x          = (const float*)d_in[0];
    const float* in_proj_w  = (const float*)d_in[1];
    const float* conv_w     = (const float*)d_in[2];
    const float* conv_b     = (const float*)d_in[3];
    const float* x_proj_w   = (const float*)d_in[4];
    const float* dt_proj_w  = (const float*)d_in[5];
    const float* dt_proj_b  = (const float*)d_in[6];
    const float* A_log      = (const float*)d_in[7];
    const float* Dp         = (const float*)d_in[8];
    const float* out_proj_w = (const float*)d_in[9];
    float* out = (float*)d_out;

    char* base = (char*)d_ws;
    // persistent region
    float* xand  = (float*)(base + 0);               // 33,554,432 (outpart late)
    float* g3buf = (float*)(base + 33554432);        // 16,777,216 (inw3 early; gated3 late)
    float* xdbl  = (float*)(base + 50331648);        //    786,432
    float* delta = (float*)(base + 51118080);        // 16,777,216 (x3 early; xpart mid)
    short* xi3   = (short*)(base + 67895296);        // 16,777,216 (outw3 late)
    float* hend  = (float*)(base + 84672512);        // 16,777,216 (NC=64)
    float* Pprod = (float*)(base + 101449728);       // 16,777,216
    char*  Q     = base + 118226944;                 // transient (~2 MB)
    // aliases
    short* x3     = (short*)delta;                   // (2048,2048)   steps 1-3
    short* inw3   = (short*)g3buf;                   // (4096,2048)   steps 1-3
    short* xw3    = (short*)Q;                       // (128,4096)    1 MB
    short* dt3    = (short*)(Q + 1048576);           // (2048,128)    0.5 MB
    short* dtw3   = (short*)(Q + 1572864);           // (2048,128)    0.5 MB
    float* xpart  = (float*)delta;                   // 16 x 2048 x 128 f32 = 16 MB
    short* gated3 = (short*)g3buf;                   // (2048,4096)   scan output
    short* outw3  = (short*)xi3;                     // (1024,4096)   steps 12-13
    float* outpart= (float*)xand;                    // 4 x 2048 x 1024 f32 = 32 MB

    dim3 blk(256);

    // 1) x -> planes
    to_planes<<<dim3(4, NTOK), blk, 0, stream>>>(x, D_MODEL, x3, NTOK, D_MODEL);
    // 2) in_proj_w -> planes
    to_planes<<<dim3(4, 2 * D_INNER), blk, 0, stream>>>(in_proj_w, D_MODEL, inw3, 2 * D_INNER, D_MODEL);
    // 3) in_proj GEMM: xand(2048,4096)
    gemm_mfma<<<dim3(NTOK / 128, (2 * D_INNER) / 128, 1), blk, 0, stream>>>(
        x3, inw3, xand, 2 * D_INNER, D_MODEL, 3 * D_MODEL / 64, 0, nullptr, 0);
    // 4) conv + silu -> xi planes
    conv_silu_planes<<<dim3(NTOK * D_INNER / 256), blk, 0, stream>>>(xand, conv_w, conv_b, xi3);
    // 5) x_proj_w -> planes (rows 96..127 zero)
    to_planes<<<dim3(8, 128), blk, 0, stream>>>(x_proj_w, D_INNER, xw3, XDBL_W, D_INNER);
    // 6) x_proj GEMM split-K=16 -> xpart (dead x3/delta region)
    gemm_mfma<<<dim3(NTOK / 128, 1, XSPLIT), blk, 0, stream>>>(
        xi3, xw3, xpart, 128, D_INNER, (3 * D_INNER / 64) / XSPLIT,
        (long long)NTOK * 128, nullptr, 0);
    // 7) reduce -> xdbl + dt3 planes (fused)
    reduce_xdbl<<<dim3(NTOK * XDBL_W / 256), blk, 0, stream>>>(xpart, xdbl, dt3);
    // 8) dt_proj_w -> planes
    to_planes<<<dim3(1, D_INNER), blk, 0, stream>>>(dt_proj_w, DT_RANK, dtw3, D_INNER, DT_RANK);
    // 9) dt_proj GEMM + bias + softplus -> delta
    gemm_mfma<<<dim3(NTOK / 128, D_INNER / 128, 1), blk, 0, stream>>>(
        dt3, dtw3, delta, D_INNER, DT_RANK, 3 * DT_RANK / 64, 0, dt_proj_b, 1);
    // 10) chunked scan (fused gate in phase3)
    {
        int total1 = BATCH * NC * D_INNER;             // 262144
        scan_phase1<<<dim3(total1 / 256), blk, 0, stream>>>(delta, xi3, xdbl, A_log, hend, Pprod);
        int total2 = BATCH * D_INNER * D_STATE;        // 65536
        scan_phase2<<<dim3(total2 / 256), blk, 0, stream>>>(hend, Pprod);
        scan_phase3<<<dim3(total1 / 256), blk, 0, stream>>>(
            delta, xi3, xdbl, A_log, Dp, hend, xand, gated3);
    }
    // 11) out_proj_w -> planes (xi3 dead)
    to_planes<<<dim3(8, D_MODEL), blk, 0, stream>>>(out_proj_w, D_INNER, outw3, D_MODEL, D_INNER);
    // 12) out_proj GEMM split-K=4 -> outpart (xand dead)
    gemm_mfma<<<dim3(NTOK / 128, D_MODEL / 128, OSPLIT), blk, 0, stream>>>(
        gated3, outw3, outpart, D_MODEL, D_INNER, (3 * D_INNER / 64) / OSPLIT,
        (long long)NTOK * D_MODEL, nullptr, 0);
    // 13) reduce -> out
    reduce_out<<<dim3(NTOK * D_MODEL / 256), blk, 0, stream>>>(outpart, out);
}